// Round 1
// baseline (2032.036 us; speedup 1.0000x reference)
//
#include <hip/hip_runtime.h>

#define BB 256
#define II 1152
#define QQ 8
#define JJ 10
#define PP 16

// ---------------------------------------------------------------------------
// Fused routing pass kernel.
//   R=0: c uniform (softmax of zeros), accumulate s0. No logit I/O.
//   R=1: bj = v0·hat (B0=0), store logits B1, softmax, accumulate s1.
//   R=2: bj = B1 + v1·hat, softmax, accumulate s2. No store.
// One thread per (b,i). hat[10][16] held in registers (~160 VGPRs).
// Block = 128 threads = one b, one 128-wide i-chunk (grid = 256*9 exact).
// ---------------------------------------------------------------------------
template <int R>
__global__ __launch_bounds__(128) void pass_kernel(
    const float* __restrict__ X,   // [B][I][Q]
    const float* __restrict__ W,   // [J][I][P][Q]
    const float* __restrict__ V,   // [B][J][P] (v from previous pass; null at R=0)
    float* __restrict__ BL,        // [B][J][I] logits scratch
    float* __restrict__ S)         // [B][J][P] accumulator (pre-zeroed)
{
    const int blk = blockIdx.x;
    const int b   = blk / 9;
    const int ic  = blk % 9;
    const int i   = ic * 128 + threadIdx.x;

    // x[b,i,:] — 32B per thread, coalesced across the wave
    const float4* xp = (const float4*)(X + (b * II + i) * QQ);
    const float4 x0 = xp[0];
    const float4 x1 = xp[1];

    // hat[j][p] = dot(W[j,i,p,:], x)
    float hat[JJ][PP];
#pragma unroll
    for (int j = 0; j < JJ; ++j) {
        const float4* wp = (const float4*)(W + (size_t)(j * II + i) * (PP * QQ));
#pragma unroll
        for (int p = 0; p < PP; ++p) {
            const float4 w0 = wp[2 * p];
            const float4 w1 = wp[2 * p + 1];
            hat[j][p] = w0.x * x0.x + w0.y * x0.y + w0.z * x0.z + w0.w * x0.w +
                        w1.x * x1.x + w1.y * x1.y + w1.z * x1.z + w1.w * x1.w;
        }
    }

    float c[JJ];
    if (R == 0) {
#pragma unroll
        for (int j = 0; j < JJ; ++j) c[j] = 0.1f;  // softmax(0) over 10
    } else {
        float bj[JJ];
#pragma unroll
        for (int j = 0; j < JJ; ++j) {
            float t = (R == 2) ? BL[(b * JJ + j) * II + i] : 0.0f;
            const float* vp = V + (b * JJ + j) * PP;  // wave-uniform address
            float d = 0.0f;
#pragma unroll
            for (int p = 0; p < PP; ++p) d += vp[p] * hat[j][p];
            bj[j] = t + d;
            if (R == 1) BL[(b * JJ + j) * II + i] = bj[j];
        }
        float m = bj[0];
#pragma unroll
        for (int j = 1; j < JJ; ++j) m = fmaxf(m, bj[j]);
        float sum = 0.0f;
#pragma unroll
        for (int j = 0; j < JJ; ++j) {
            c[j] = __expf(bj[j] - m);
            sum += c[j];
        }
        const float inv = 1.0f / sum;
#pragma unroll
        for (int j = 0; j < JJ; ++j) c[j] *= inv;
    }

    // partial s[b,j,p]: butterfly-reduce over the 64-lane wave, lane0 atomics.
    const int lane = threadIdx.x & 63;
#pragma unroll
    for (int j = 0; j < JJ; ++j) {
#pragma unroll
        for (int p = 0; p < PP; ++p) {
            float v = c[j] * hat[j][p];
            v += __shfl_down(v, 32, 64);
            v += __shfl_down(v, 16, 64);
            v += __shfl_down(v, 8, 64);
            v += __shfl_down(v, 4, 64);
            v += __shfl_down(v, 2, 64);
            v += __shfl_down(v, 1, 64);
            if (lane == 0) atomicAdd(&S[(b * JJ + j) * PP + p], v);
        }
    }
}

// ---------------------------------------------------------------------------
// squash: v = s * |s|^2 / (1+|s|^2) / sqrt(|s|^2 + 1e-7), per (b,j) row of 16.
// ---------------------------------------------------------------------------
__global__ __launch_bounds__(256) void squash_kernel(const float* __restrict__ S,
                                                     float* __restrict__ V)
{
    const int idx = blockIdx.x * blockDim.x + threadIdx.x;  // (b*J + j)
    if (idx >= BB * JJ) return;
    const float4* sp = (const float4*)(S + idx * PP);
    float4 a = sp[0], b4 = sp[1], c4 = sp[2], d4 = sp[3];
    float s2 = a.x * a.x + a.y * a.y + a.z * a.z + a.w * a.w +
               b4.x * b4.x + b4.y * b4.y + b4.z * b4.z + b4.w * b4.w +
               c4.x * c4.x + c4.y * c4.y + c4.z * c4.z + c4.w * c4.w +
               d4.x * d4.x + d4.y * d4.y + d4.z * d4.z + d4.w * d4.w;
    const float scale = s2 / (1.0f + s2) / sqrtf(s2 + 1e-7f);
    float4* vp = (float4*)(V + idx * PP);
    a.x *= scale; a.y *= scale; a.z *= scale; a.w *= scale;
    b4.x *= scale; b4.y *= scale; b4.z *= scale; b4.w *= scale;
    c4.x *= scale; c4.y *= scale; c4.z *= scale; c4.w *= scale;
    d4.x *= scale; d4.y *= scale; d4.z *= scale; d4.w *= scale;
    vp[0] = a; vp[1] = b4; vp[2] = c4; vp[3] = d4;
}

extern "C" void kernel_launch(void* const* d_in, const int* in_sizes, int n_in,
                              void* d_out, int out_size, void* d_ws, size_t ws_size,
                              hipStream_t stream)
{
    const float* X = (const float*)d_in[0];  // [256][1152][8]
    const float* W = (const float*)d_in[1];  // [10][1152][16][8]
    float* out = (float*)d_out;              // [256][10][16]

    float* s    = (float*)d_ws;      // 40960 floats
    float* v    = s + BB * JJ * PP;  // 40960 floats
    float* blog = v + BB * JJ * PP;  // 2949120 floats  (total ~12.1 MB)

    const int grid = BB * 9;  // 2304 blocks of 128 threads (one (b, i-chunk) each)

    hipMemsetAsync(s, 0, BB * JJ * PP * sizeof(float), stream);
    pass_kernel<0><<<grid, 128, 0, stream>>>(X, W, nullptr, blog, s);
    squash_kernel<<<10, 256, 0, stream>>>(s, v);  // v0

    hipMemsetAsync(s, 0, BB * JJ * PP * sizeof(float), stream);
    pass_kernel<1><<<grid, 128, 0, stream>>>(X, W, v, blog, s);
    squash_kernel<<<10, 256, 0, stream>>>(s, v);  // v1

    hipMemsetAsync(s, 0, BB * JJ * PP * sizeof(float), stream);
    pass_kernel<2><<<grid, 128, 0, stream>>>(X, W, v, blog, s);
    squash_kernel<<<10, 256, 0, stream>>>(s, out);
}

// Round 2
// 676.922 us; speedup vs baseline: 3.0019x; 3.0019x over previous
//
#include <hip/hip_runtime.h>

#define BB 256
#define II 1152
#define QQ 8
#define JJ 10
#define PP 16

#define BT 16            // b per block
#define IT 32            // i per block
#define NBT (BB / BT)    // 16
#define NIT (II / IT)    // 36

#define XROW (IT * QQ)   // 256 floats per b-row of staged x
#define CROW (IT * 12)   // 384 floats per b-row of staged c (12 = 10 + pad, keeps 16B align)

// ---------------------------------------------------------------------------
// Fused routing pass. Block = 256 threads = (16 b) x (16 lanes).
//   Stage x[16b][32i][8q] in LDS (read global X once).
//   Sweep A (R>0): thread=(b, i-lane), 2 i's each. logits bj = BLprev + v.hat,
//                  softmax over j -> c staged in LDS (and BL written at R==1).
//   Sweep B: thread=(b, p), loops all 32 i: s_acc[j] += c[j] * (W[j,i,p,:].x),
//            10 register accumulators, 10 atomicAdds to S at the end.
// ---------------------------------------------------------------------------
template <int R>
__global__ __launch_bounds__(256, 4) void pass_kernel(
    const float* __restrict__ X,   // [B][I][Q]
    const float* __restrict__ W,   // [J][I][P][Q]
    const float* __restrict__ V,   // [B][J][P] (null at R==0)
    float* __restrict__ BL,        // [B][J][I] cumulative logits
    float* __restrict__ S)         // [B][J][P] pre-zeroed accumulator
{
    __shared__ float xs[BT * XROW];  // 16 KB
    __shared__ float cs[BT * CROW];  // 24 KB

    const int bt = blockIdx.x & (NBT - 1);
    const int it = blockIdx.x >> 4;
    const int b0 = bt * BT;
    const int i0 = it * IT;
    const int tid = threadIdx.x;

    // ---- stage x tile: 16b x 32i x 8q = 4096 floats = 1024 float4, 4 per thread
    {
#pragma unroll
        for (int k = 0; k < 4; ++k) {
            const int f4  = tid + k * 256;      // 0..1023
            const int b_l = f4 >> 6;            // 64 float4 per b
            const int r   = f4 & 63;
            const float4 v4 = ((const float4*)(X + ((size_t)(b0 + b_l) * II + i0) * QQ))[r];
            ((float4*)(xs + b_l * XROW))[r] = v4;
        }
    }
    __syncthreads();

    // ---- sweep A: logits + softmax -> cs (skipped at R==0: c uniform 0.1)
    if (R > 0) {
        const int b_l = tid >> 4;
        const int il  = tid & 15;
        const int b   = b0 + b_l;

        float xr[2][8];
#pragma unroll
        for (int ii = 0; ii < 2; ++ii) {
            const float4 a0 = ((const float4*)(xs + b_l * XROW + (ii * 16 + il) * QQ))[0];
            const float4 a1 = ((const float4*)(xs + b_l * XROW + (ii * 16 + il) * QQ))[1];
            xr[ii][0] = a0.x; xr[ii][1] = a0.y; xr[ii][2] = a0.z; xr[ii][3] = a0.w;
            xr[ii][4] = a1.x; xr[ii][5] = a1.y; xr[ii][6] = a1.z; xr[ii][7] = a1.w;
        }

        float bj[2][JJ];
#pragma unroll
        for (int ii = 0; ii < 2; ++ii)
#pragma unroll
            for (int j = 0; j < JJ; ++j)
                bj[ii][j] = (R == 2) ? BL[((size_t)b * JJ + j) * II + i0 + ii * 16 + il]
                                     : 0.0f;

#pragma unroll
        for (int j = 0; j < JJ; ++j) {
            float vv[16];
            const float4* vp = (const float4*)(V + ((size_t)b * JJ + j) * PP);
            const float4 v0 = vp[0], v1 = vp[1], v2 = vp[2], v3 = vp[3];
            vv[0] = v0.x; vv[1] = v0.y; vv[2] = v0.z; vv[3] = v0.w;
            vv[4] = v1.x; vv[5] = v1.y; vv[6] = v1.z; vv[7] = v1.w;
            vv[8] = v2.x; vv[9] = v2.y; vv[10] = v2.z; vv[11] = v2.w;
            vv[12] = v3.x; vv[13] = v3.y; vv[14] = v3.z; vv[15] = v3.w;
#pragma unroll
            for (int ii = 0; ii < 2; ++ii) {
                const float* wp = W + ((size_t)j * II + i0 + ii * 16 + il) * (PP * QQ);
                float t = 0.0f;
#pragma unroll
                for (int p = 0; p < PP; ++p) {
                    const float4 w0 = ((const float4*)(wp + p * QQ))[0];
                    const float4 w1 = ((const float4*)(wp + p * QQ))[1];
                    const float h = w0.x * xr[ii][0] + w0.y * xr[ii][1] +
                                    w0.z * xr[ii][2] + w0.w * xr[ii][3] +
                                    w1.x * xr[ii][4] + w1.y * xr[ii][5] +
                                    w1.z * xr[ii][6] + w1.w * xr[ii][7];
                    t += vv[p] * h;
                }
                bj[ii][j] += t;
            }
        }

#pragma unroll
        for (int ii = 0; ii < 2; ++ii) {
            float m = bj[ii][0];
#pragma unroll
            for (int j = 1; j < JJ; ++j) m = fmaxf(m, bj[ii][j]);
            float c[JJ], sum = 0.0f;
#pragma unroll
            for (int j = 0; j < JJ; ++j) { c[j] = __expf(bj[ii][j] - m); sum += c[j]; }
            const float inv = 1.0f / sum;
            float* crow = cs + b_l * CROW + (ii * 16 + il) * 12;
#pragma unroll
            for (int j = 0; j < JJ; ++j) crow[j] = c[j] * inv;
            if (R == 1) {
#pragma unroll
                for (int j = 0; j < JJ; ++j)
                    BL[((size_t)b * JJ + j) * II + i0 + ii * 16 + il] = bj[ii][j];
            }
        }
    }
    __syncthreads();

    // ---- sweep B: thread = (b, p); loop all 32 i; 10 reg accumulators
    {
        const int b_l = tid >> 4;
        const int p   = tid & 15;
        const int b   = b0 + b_l;

        float sacc[JJ];
#pragma unroll
        for (int j = 0; j < JJ; ++j) sacc[j] = 0.0f;

        for (int i = 0; i < IT; ++i) {
            const float4 a0 = ((const float4*)(xs + b_l * XROW + i * QQ))[0];
            const float4 a1 = ((const float4*)(xs + b_l * XROW + i * QQ))[1];

            float c[JJ];
            if (R == 0) {
#pragma unroll
                for (int j = 0; j < JJ; ++j) c[j] = 0.1f;
            } else {
                const float* crow = cs + b_l * CROW + i * 12;
                const float4 c0 = ((const float4*)crow)[0];
                const float4 c1 = ((const float4*)crow)[1];
                c[0] = c0.x; c[1] = c0.y; c[2] = c0.z; c[3] = c0.w;
                c[4] = c1.x; c[5] = c1.y; c[6] = c1.z; c[7] = c1.w;
                c[8] = crow[8]; c[9] = crow[9];
            }

#pragma unroll
            for (int j = 0; j < JJ; ++j) {
                const float* wp = W + (((size_t)j * II + i0 + i) * PP + p) * QQ;
                const float4 w0 = ((const float4*)wp)[0];
                const float4 w1 = ((const float4*)wp)[1];
                const float h = w0.x * a0.x + w0.y * a0.y + w0.z * a0.z + w0.w * a0.w +
                                w1.x * a1.x + w1.y * a1.y + w1.z * a1.z + w1.w * a1.w;
                sacc[j] += c[j] * h;
            }
        }

#pragma unroll
        for (int j = 0; j < JJ; ++j)
            atomicAdd(&S[((size_t)b * JJ + j) * PP + p], sacc[j]);
    }
}

// ---------------------------------------------------------------------------
// squash: v = s * |s|^2 / (1+|s|^2) / sqrt(|s|^2 + 1e-7), per (b,j) row of 16.
// ---------------------------------------------------------------------------
__global__ __launch_bounds__(256) void squash_kernel(const float* __restrict__ S,
                                                     float* __restrict__ V)
{
    const int idx = blockIdx.x * blockDim.x + threadIdx.x;  // (b*J + j)
    if (idx >= BB * JJ) return;
    const float4* sp = (const float4*)(S + idx * PP);
    float4 a = sp[0], b4 = sp[1], c4 = sp[2], d4 = sp[3];
    float s2 = a.x * a.x + a.y * a.y + a.z * a.z + a.w * a.w +
               b4.x * b4.x + b4.y * b4.y + b4.z * b4.z + b4.w * b4.w +
               c4.x * c4.x + c4.y * c4.y + c4.z * c4.z + c4.w * c4.w +
               d4.x * d4.x + d4.y * d4.y + d4.z * d4.z + d4.w * d4.w;
    const float scale = s2 / (1.0f + s2) / sqrtf(s2 + 1e-7f);
    float4* vp = (float4*)(V + idx * PP);
    a.x *= scale; a.y *= scale; a.z *= scale; a.w *= scale;
    b4.x *= scale; b4.y *= scale; b4.z *= scale; b4.w *= scale;
    c4.x *= scale; c4.y *= scale; c4.z *= scale; c4.w *= scale;
    d4.x *= scale; d4.y *= scale; d4.z *= scale; d4.w *= scale;
    vp[0] = a; vp[1] = b4; vp[2] = c4; vp[3] = d4;
}

extern "C" void kernel_launch(void* const* d_in, const int* in_sizes, int n_in,
                              void* d_out, int out_size, void* d_ws, size_t ws_size,
                              hipStream_t stream)
{
    const float* X = (const float*)d_in[0];  // [256][1152][8]
    const float* W = (const float*)d_in[1];  // [10][1152][16][8]
    float* out = (float*)d_out;              // [256][10][16]

    float* s    = (float*)d_ws;      // 40960 floats
    float* v    = s + BB * JJ * PP;  // 40960 floats
    float* blog = v + BB * JJ * PP;  // 2949120 floats (total ~12.1 MB)

    const int grid = NBT * NIT;  // 576 blocks

    hipMemsetAsync(s, 0, BB * JJ * PP * sizeof(float), stream);
    pass_kernel<0><<<grid, 256, 0, stream>>>(X, W, nullptr, blog, s);
    squash_kernel<<<10, 256, 0, stream>>>(s, v);  // v0

    hipMemsetAsync(s, 0, BB * JJ * PP * sizeof(float), stream);
    pass_kernel<1><<<grid, 256, 0, stream>>>(X, W, v, blog, s);
    squash_kernel<<<10, 256, 0, stream>>>(s, v);  // v1

    hipMemsetAsync(s, 0, BB * JJ * PP * sizeof(float), stream);
    pass_kernel<2><<<grid, 256, 0, stream>>>(X, W, v, blog, s);
    squash_kernel<<<10, 256, 0, stream>>>(s, out);
}

// Round 3
// 275.113 us; speedup vs baseline: 7.3862x; 2.4605x over previous
//
#include <hip/hip_runtime.h>

#define BB 256
#define II 1152
#define QQ 8
#define JJ 10
#define PP 16

#define BT 8             // b per block (128 threads = 8 b-lanes x 16 p-lanes)
#define IT 16            // i per block
#define NBT (BB / BT)    // 32
#define NIT (II / IT)    // 72
#define XROW (IT * QQ + 4)  // 132 floats: +4 pad shifts banks by 4 per b-lane -> conflict-free

// ---------------------------------------------------------------------------
// Single-sweep fused routing pass. Thread = (b_l, p). Loop i over the tile:
//   h[j] = W[j,i,p,:]·x[i,:]          (lanes p=0..15 -> contiguous 512B, coalesced)
//   bj[j] = BLprev + reduce_p(v[j,p]·h[j])   (4 shfl_xor over the 16 p-lanes)
//   c = softmax_j(bj)  (computed redundantly on all p-lanes)
//   sacc[j] += c[j]·h[j]              (same h serves logits AND s — W read ONCE)
// R=0: c uniform 0.1, no logit work. R=1: store cumulative logits. R=2: load them.
// ---------------------------------------------------------------------------
template <int R>
__global__ __launch_bounds__(128, 4) void pass_kernel(
    const float* __restrict__ X,   // [B][I][Q]
    const float* __restrict__ W,   // [J][I][P][Q]
    const float* __restrict__ V,   // [B][J][P] (null at R==0)
    float* __restrict__ BL,        // [B][J][I] cumulative logits
    float* __restrict__ S)         // [B][J][P] pre-zeroed accumulator
{
    __shared__ float xs[BT * XROW];  // ~4.2 KB

    const int bt = blockIdx.x & (NBT - 1);   // consecutive blocks share the i-tile (W reuse in L2)
    const int it = blockIdx.x >> 5;
    const int b0 = bt * BT;
    const int i0 = it * IT;
    const int tid = threadIdx.x;

    // ---- stage x tile: 8 b x 16 i x 8 q = 1024 floats = 256 float4, 2 per thread
#pragma unroll
    for (int k = 0; k < 2; ++k) {
        const int f4  = tid + k * 128;   // 0..255
        const int b_l = f4 >> 5;         // 32 float4 per b
        const int r   = f4 & 31;
        const float4 v4 = ((const float4*)(X + ((size_t)(b0 + b_l) * II + i0) * QQ))[r];
        ((float4*)(xs + b_l * XROW))[r] = v4;
    }
    __syncthreads();

    const int b_l = tid >> 4;
    const int p   = tid & 15;
    const int b   = b0 + b_l;

    // v[j] for this (b,p) — hoisted out of the i-loop (coalesced 64B per (b_l,j))
    float vv[JJ];
    if (R > 0) {
#pragma unroll
        for (int j = 0; j < JJ; ++j)
            vv[j] = V[((size_t)b * JJ + j) * PP + p];
    }

    float sacc[JJ];
#pragma unroll
    for (int j = 0; j < JJ; ++j) sacc[j] = 0.0f;

    for (int i = 0; i < IT; ++i) {
        const float4 a0 = *(const float4*)(xs + b_l * XROW + i * QQ);
        const float4 a1 = *(const float4*)(xs + b_l * XROW + i * QQ + 4);

        float h[JJ];
#pragma unroll
        for (int j = 0; j < JJ; ++j) {
            const float4* wp = (const float4*)(W + (((size_t)j * II + i0 + i) * PP + p) * QQ);
            const float4 w0 = wp[0];
            const float4 w1 = wp[1];
            h[j] = w0.x * a0.x + w0.y * a0.y + w0.z * a0.z + w0.w * a0.w +
                   w1.x * a1.x + w1.y * a1.y + w1.z * a1.z + w1.w * a1.w;
        }

        float c[JJ];
        if (R == 0) {
#pragma unroll
            for (int j = 0; j < JJ; ++j) c[j] = 0.1f;
        } else {
            float bj[JJ];
#pragma unroll
            for (int j = 0; j < JJ; ++j) {
                float d = vv[j] * h[j];
                d += __shfl_xor(d, 1, 64);
                d += __shfl_xor(d, 2, 64);
                d += __shfl_xor(d, 4, 64);
                d += __shfl_xor(d, 8, 64);
                float t = (R == 2) ? BL[((size_t)b * JJ + j) * II + i0 + i] : 0.0f;
                bj[j] = t + d;
            }
            if (R == 1) {
                if (p == 0) {
#pragma unroll
                    for (int j = 0; j < JJ; ++j)
                        BL[((size_t)b * JJ + j) * II + i0 + i] = bj[j];
                }
            }
            float m = bj[0];
#pragma unroll
            for (int j = 1; j < JJ; ++j) m = fmaxf(m, bj[j]);
            float sum = 0.0f;
#pragma unroll
            for (int j = 0; j < JJ; ++j) { c[j] = __expf(bj[j] - m); sum += c[j]; }
            const float inv = 1.0f / sum;
#pragma unroll
            for (int j = 0; j < JJ; ++j) c[j] *= inv;
        }

#pragma unroll
        for (int j = 0; j < JJ; ++j) sacc[j] += c[j] * h[j];
    }

#pragma unroll
    for (int j = 0; j < JJ; ++j)
        atomicAdd(&S[((size_t)b * JJ + j) * PP + p], sacc[j]);
}

// ---------------------------------------------------------------------------
// squash: v = s * |s|^2 / (1+|s|^2) / sqrt(|s|^2 + 1e-7), per (b,j) row of 16.
// ---------------------------------------------------------------------------
__global__ __launch_bounds__(256) void squash_kernel(const float* __restrict__ S,
                                                     float* __restrict__ V)
{
    const int idx = blockIdx.x * blockDim.x + threadIdx.x;  // (b*J + j)
    if (idx >= BB * JJ) return;
    const float4* sp = (const float4*)(S + idx * PP);
    float4 a = sp[0], b4 = sp[1], c4 = sp[2], d4 = sp[3];
    float s2 = a.x * a.x + a.y * a.y + a.z * a.z + a.w * a.w +
               b4.x * b4.x + b4.y * b4.y + b4.z * b4.z + b4.w * b4.w +
               c4.x * c4.x + c4.y * c4.y + c4.z * c4.z + c4.w * c4.w +
               d4.x * d4.x + d4.y * d4.y + d4.z * d4.z + d4.w * d4.w;
    const float scale = s2 / (1.0f + s2) / sqrtf(s2 + 1e-7f);
    float4* vp = (float4*)(V + idx * PP);
    a.x *= scale; a.y *= scale; a.z *= scale; a.w *= scale;
    b4.x *= scale; b4.y *= scale; b4.z *= scale; b4.w *= scale;
    c4.x *= scale; c4.y *= scale; c4.z *= scale; c4.w *= scale;
    d4.x *= scale; d4.y *= scale; d4.z *= scale; d4.w *= scale;
    vp[0] = a; vp[1] = b4; vp[2] = c4; vp[3] = d4;
}

extern "C" void kernel_launch(void* const* d_in, const int* in_sizes, int n_in,
                              void* d_out, int out_size, void* d_ws, size_t ws_size,
                              hipStream_t stream)
{
    const float* X = (const float*)d_in[0];  // [256][1152][8]
    const float* W = (const float*)d_in[1];  // [10][1152][16][8]
    float* out = (float*)d_out;              // [256][10][16]

    float* s    = (float*)d_ws;      // 40960 floats
    float* v    = s + BB * JJ * PP;  // 40960 floats
    float* blog = v + BB * JJ * PP;  // 2949120 floats (total ~12.1 MB)

    const int grid = NBT * NIT;  // 2304 blocks of 128 threads

    hipMemsetAsync(s, 0, BB * JJ * PP * sizeof(float), stream);
    pass_kernel<0><<<grid, 128, 0, stream>>>(X, W, nullptr, blog, s);
    squash_kernel<<<10, 256, 0, stream>>>(s, v);  // v0

    hipMemsetAsync(s, 0, BB * JJ * PP * sizeof(float), stream);
    pass_kernel<1><<<grid, 128, 0, stream>>>(X, W, v, blog, s);
    squash_kernel<<<10, 256, 0, stream>>>(s, v);  // v1

    hipMemsetAsync(s, 0, BB * JJ * PP * sizeof(float), stream);
    pass_kernel<2><<<grid, 128, 0, stream>>>(X, W, v, blog, s);
    squash_kernel<<<10, 256, 0, stream>>>(s, out);
}